// Round 2
// baseline (193.633 us; speedup 1.0000x reference)
//
#include <hip/hip_runtime.h>
#include <hip/hip_fp16.h>

// RoIAlignRotated on MI355X — R4.
// R3 -> R4 (theory: main kernel latency-bound, capped by GRID size not LDS:
// 1000 blocks x 4 waves = 4000 waves on an 8192-wave machine -> 30% occupancy).
// 1) main kernel: 2 blocks per ROI, bin-split (block 2n+h does bins [25h,25h+25)).
//    -> 2000 blocks = 8000 waves (full machine). Same total gather instruction
//    count and same 512B/wave gather width as R3 (a channel split would double
//    instructions and split cache lines).
// 2) s_out shrinks to [25][258] fp16 -> ~19.4 KB LDS -> 8 blocks/CU cap.

#define B_ 2
#define C_ 256
#define H_ 200
#define W_ 200
#define OUTHW 7
#define GRID_S 14          // OUTHW * sampling_ratio(2)
#define NSAMP 196          // 14*14
#define ELEMS (C_ * OUTHW * OUTHW)  // 12544

// ---------- NCHW f32 -> NHWC fp16, LDS-tiled ----------
__global__ __launch_bounds__(256) void transpose_h_kernel(
    const float* __restrict__ feat, __half* __restrict__ featT)
{
    __shared__ float tile[64][65];   // [c_local][x_local], stride 65
    const int x0   = blockIdx.x * 64;
    const int c0   = blockIdx.y * 64;
    const int yb   = blockIdx.z;     // b*H_ + y
    const int y    = yb % H_;
    const int b    = yb / H_;
    const int t    = threadIdx.x;
    const int lane = t & 63;
    const int grp  = t >> 6;         // 0..3
    const int nx   = min(64, W_ - x0);

    // read: lanes along x -> 256B coalesced per instruction
    if (lane < nx) {
        #pragma unroll
        for (int i = 0; i < 16; ++i) {
            const int cl = grp * 16 + i;
            tile[cl][lane] =
                feat[((size_t)(b * C_ + c0 + cl) * H_ + y) * W_ + x0 + lane];
        }
    }
    __syncthreads();

    // write: each lane packs 8 contiguous channels of one pixel -> 16B store.
    // Wave covers 8 pixels x 64 channels: 8 x 128B full-cache-line segments.
    const int c = (t & 7) * 8;
    #pragma unroll
    for (int pass = 0; pass < 2; ++pass) {
        const int p = pass * 32 + (t >> 3);
        if (p < nx) {
            union { __half h[8]; uint4 u; } pk;
            #pragma unroll
            for (int k = 0; k < 8; ++k)
                pk.h[k] = __float2half(tile[c + k][p]);
            *reinterpret_cast<uint4*>(
                &featT[((size_t)(b * H_ + y) * W_ + x0 + p) * C_ + c0 + c]) = pk.u;
        }
    }
}

// ---------- per-roi sample table (channel-independent) ----------
__device__ __forceinline__ void build_table(
    const float* __restrict__ rois, int n, int t,
    float s_w[4][NSAMP], int s_idx[4][NSAMP], int pix_stride, int fold_batch,
    int* s_b)
{
    const float spatial_scale = 0.25f;
    if (t == 0 && s_b) *s_b = (int)rois[n * 6 + 0];
    if (t < NSAMP) {
        const int   b  = (int)rois[n * 6 + 0];
        const float cx = rois[n * 6 + 1] * spatial_scale;
        const float cy = rois[n * 6 + 2] * spatial_scale;
        const float rw = fmaxf(rois[n * 6 + 3] * spatial_scale, 1.0f);
        const float rh = fmaxf(rois[n * 6 + 4] * spatial_scale, 1.0f);
        const float th = rois[n * 6 + 5];
        const float cosv = cosf(th), sinv = sinf(th);

        const float bin_h = rh * (1.0f / OUTHW);
        const float bin_w = rw * (1.0f / OUTHW);
        const int row = t / GRID_S;
        const int col = t % GRID_S;

        const float yy = -rh * 0.5f + ((float)row + 0.5f) * 0.5f * bin_h;
        const float xx = -rw * 0.5f + ((float)col + 0.5f) * 0.5f * bin_w;

        const float y = yy * cosv - xx * sinv + cy;
        const float x = yy * sinv + xx * cosv + cx;

        const bool inside = (y >= -1.0f) && (y <= (float)H_) &&
                            (x >= -1.0f) && (x <= (float)W_);

        const float yc = fmaxf(y, 0.0f);
        const float xc = fmaxf(x, 0.0f);
        const float fy = floorf(yc);
        const float fx = floorf(xc);
        int yl = min((int)fy, H_ - 1);
        int xl = min((int)fx, W_ - 1);
        const int yh = min(yl + 1, H_ - 1);
        const int xh = min(xl + 1, W_ - 1);
        const float ly = (fy >= (float)(H_ - 1)) ? 0.0f : (yc - fy);
        const float lx = (fx >= (float)(W_ - 1)) ? 0.0f : (xc - fx);
        const float hy = 1.0f - ly;
        const float hx = 1.0f - lx;

        const float m = inside ? 0.25f : 0.0f;   // fold inside-mask + 2x2 mean
        s_w[0][t] = hy * hx * m;
        s_w[1][t] = hy * lx * m;
        s_w[2][t] = ly * hx * m;
        s_w[3][t] = ly * lx * m;
        const int bb = fold_batch ? b : 0;
        s_idx[0][t] = ((bb * H_ + yl) * W_ + xl) * pix_stride;
        s_idx[1][t] = ((bb * H_ + yl) * W_ + xh) * pix_stride;
        s_idx[2][t] = ((bb * H_ + yh) * W_ + xl) * pix_stride;
        s_idx[3][t] = ((bb * H_ + yh) * W_ + xh) * pix_stride;
    }
}

// ---------- main kernel: 2 blocks/ROI (bin-split), NHWC fp16 gathers --------
__global__ __launch_bounds__(256) void roi_main_nhwc_h(
    const __half* __restrict__ featT,
    const float* __restrict__ rois,
    float* __restrict__ out)
{
    __shared__ float  s_w[4][NSAMP];        // 3136 B
    __shared__ int    s_idx[4][NSAMP];      // 3136 B
    __shared__ __half s_out[25][258];       // 12900 B; total ~19.4 KB -> 8 blk/CU

    const int n = blockIdx.x >> 1;
    const int h = blockIdx.x & 1;           // bin half: 0 -> bins 0..24, 1 -> 25..48
    const int t = threadIdx.x;
    build_table(rois, n, t, s_w, s_idx, C_, 1, nullptr);
    __syncthreads();

    const int lane  = t & 63;
    const int wave  = t >> 6;
    const int cbase = lane * 4;             // 4 channels per lane
    const int b0    = h * 25;
    const int nb    = h ? 24 : 25;

    for (int bl = wave; bl < nb; bl += 4) {
        const int bin = b0 + bl;
        const int oy = bin / OUTHW;
        const int ox = bin - oy * OUTHW;
        float a0 = 0.f, a1 = 0.f, a2 = 0.f, a3 = 0.f;
        #pragma unroll
        for (int j = 0; j < 2; ++j) {
            #pragma unroll
            for (int i = 0; i < 2; ++i) {
                const int s = (oy * 2 + j) * GRID_S + (ox * 2 + i);
                #pragma unroll
                for (int q = 0; q < 4; ++q) {
                    const float w = s_w[q][s];
                    const __half2* p =
                        (const __half2*)(featT + s_idx[q][s] + cbase);
                    const float2 fa = __half22float2(p[0]);
                    const float2 fb = __half22float2(p[1]);
                    a0 += w * fa.x; a1 += w * fa.y;
                    a2 += w * fb.x; a3 += w * fb.y;
                }
            }
        }
        // channel c=cbase+k stored at col k*64+lane: contiguous fp16 across
        // lanes -> 2 lanes per dword-bank = free
        s_out[bl][0 * 64 + lane] = __float2half(a0);
        s_out[bl][1 * 64 + lane] = __float2half(a1);
        s_out[bl][2 * 64 + lane] = __float2half(a2);
        s_out[bl][3 * 64 + lane] = __float2half(a3);
    }
    __syncthreads();

    // stores: this block's bins for all 256 channels (runs of nb contiguous
    // floats per channel), nontemporal stream
    float* __restrict__ ob = out + (size_t)n * ELEMS + b0;
    const int tot = C_ * nb;                // 6400 or 6144
    for (int k = 0; k < 25; ++k) {
        const int e = t + k * 256;
        if (e < tot) {
            const int c  = e / nb;
            const int bl = e - c * nb;
            __builtin_nontemporal_store(
                __half2float(s_out[bl][(c & 3) * 64 + (c >> 2)]),
                &ob[c * 49 + bl]);
        }
    }
}

// ---------- fallback (known-correct NCHW path, no workspace) ----------
__global__ __launch_bounds__(256) void roi_main_nchw(
    const float* __restrict__ feat,
    const float* __restrict__ rois,
    float* __restrict__ out)
{
    const int n = blockIdx.x;
    const int t = threadIdx.x;
    __shared__ float s_w[4][NSAMP];
    __shared__ int   s_idx[4][NSAMP];
    __shared__ int   s_b;

    build_table(rois, n, t, s_w, s_idx, 1, 0, &s_b);
    __syncthreads();

    const float* __restrict__ fb = feat + (size_t)s_b * (size_t)(C_ * H_ * W_);
    float* __restrict__ ob = out + (size_t)n * (size_t)ELEMS;

    for (int e = t; e < ELEMS; e += 256) {
        const int c   = e / 49;
        const int bin = e - c * 49;
        const int oy  = bin / 7;
        const int ox  = bin - oy * 7;
        const float* __restrict__ fc = fb + c * (H_ * W_);
        float acc = 0.0f;
        #pragma unroll
        for (int j = 0; j < 2; ++j) {
            #pragma unroll
            for (int i = 0; i < 2; ++i) {
                const int s = (oy * 2 + j) * GRID_S + (ox * 2 + i);
                acc += s_w[0][s] * fc[s_idx[0][s]];
                acc += s_w[1][s] * fc[s_idx[1][s]];
                acc += s_w[2][s] * fc[s_idx[2][s]];
                acc += s_w[3][s] * fc[s_idx[3][s]];
            }
        }
        ob[e] = acc;
    }
}

extern "C" void kernel_launch(void* const* d_in, const int* in_sizes, int n_in,
                              void* d_out, int out_size, void* d_ws, size_t ws_size,
                              hipStream_t stream) {
    const float* feat = (const float*)d_in[0];
    const float* rois = (const float*)d_in[1];
    float* out = (float*)d_out;
    const int N = in_sizes[1] / 6;  // 1000

    const size_t need = (size_t)B_ * H_ * W_ * C_ * sizeof(__half); // 41 MB
    if (ws_size >= need) {
        __half* featT = (__half*)d_ws;
        dim3 tg((W_ + 63) / 64, C_ / 64, H_ * B_);
        transpose_h_kernel<<<tg, 256, 0, stream>>>(feat, featT);
        roi_main_nhwc_h<<<N * 2, 256, 0, stream>>>(featT, rois, out);
    } else {
        roi_main_nchw<<<N, 256, 0, stream>>>(feat, rois, out);
    }
}

// Round 3
// 185.239 us; speedup vs baseline: 1.0453x; 1.0453x over previous
//
#include <hip/hip_runtime.h>
#include <hip/hip_fp16.h>

// RoIAlignRotated on MI355X — R5.
// R4 -> R5 post-mortem: more waves made it WORSE (50.5 -> 62.5 us) — the
// kernel is MLP-starved, not wave-starved (VGPR=36 => <1 outstanding gather
// per wave; 0.8 B/cy/wave delivered). R5:
// 1) revert to 1000 blocks x 4 waves, whole ROI per block (coalesced writes,
//    one table build, L1 locality).
// 2) paired gathers: lanes 0-31 read corner qA, lanes 32-63 corner qB, 16B
//    per lane (8 fp16 ch) -> 1KB per instruction, 2 pixels; instr count halves.
// 3) all 8 loads of a bin issued before any consumption (explicit uint4 rv[8])
//    -> 8KB in flight per wave. Half-sums combined via __shfl_xor(.,32).

#define B_ 2
#define C_ 256
#define H_ 200
#define W_ 200
#define OUTHW 7
#define GRID_S 14          // OUTHW * sampling_ratio(2)
#define NSAMP 196          // 14*14
#define ELEMS (C_ * OUTHW * OUTHW)  // 12544

// ---------- NCHW f32 -> NHWC fp16, LDS-tiled ----------
__global__ __launch_bounds__(256) void transpose_h_kernel(
    const float* __restrict__ feat, __half* __restrict__ featT)
{
    __shared__ float tile[64][65];   // [c_local][x_local], stride 65
    const int x0   = blockIdx.x * 64;
    const int c0   = blockIdx.y * 64;
    const int yb   = blockIdx.z;     // b*H_ + y
    const int y    = yb % H_;
    const int b    = yb / H_;
    const int t    = threadIdx.x;
    const int lane = t & 63;
    const int grp  = t >> 6;         // 0..3
    const int nx   = min(64, W_ - x0);

    // read: lanes along x -> 256B coalesced per instruction
    if (lane < nx) {
        #pragma unroll
        for (int i = 0; i < 16; ++i) {
            const int cl = grp * 16 + i;
            tile[cl][lane] =
                feat[((size_t)(b * C_ + c0 + cl) * H_ + y) * W_ + x0 + lane];
        }
    }
    __syncthreads();

    // write: each lane packs 8 contiguous channels of one pixel -> 16B store.
    // Wave covers 8 pixels x 64 channels: 8 x 128B full-cache-line segments.
    const int c = (t & 7) * 8;
    #pragma unroll
    for (int pass = 0; pass < 2; ++pass) {
        const int p = pass * 32 + (t >> 3);
        if (p < nx) {
            union { __half h[8]; uint4 u; } pk;
            #pragma unroll
            for (int k = 0; k < 8; ++k)
                pk.h[k] = __float2half(tile[c + k][p]);
            *reinterpret_cast<uint4*>(
                &featT[((size_t)(b * H_ + y) * W_ + x0 + p) * C_ + c0 + c]) = pk.u;
        }
    }
}

// ---------- per-roi sample table (channel-independent) ----------
__device__ __forceinline__ void build_table(
    const float* __restrict__ rois, int n, int t,
    float s_w[4][NSAMP], int s_idx[4][NSAMP], int pix_stride, int fold_batch,
    int* s_b)
{
    const float spatial_scale = 0.25f;
    if (t == 0 && s_b) *s_b = (int)rois[n * 6 + 0];
    if (t < NSAMP) {
        const int   b  = (int)rois[n * 6 + 0];
        const float cx = rois[n * 6 + 1] * spatial_scale;
        const float cy = rois[n * 6 + 2] * spatial_scale;
        const float rw = fmaxf(rois[n * 6 + 3] * spatial_scale, 1.0f);
        const float rh = fmaxf(rois[n * 6 + 4] * spatial_scale, 1.0f);
        const float th = rois[n * 6 + 5];
        const float cosv = cosf(th), sinv = sinf(th);

        const float bin_h = rh * (1.0f / OUTHW);
        const float bin_w = rw * (1.0f / OUTHW);
        const int row = t / GRID_S;
        const int col = t % GRID_S;

        const float yy = -rh * 0.5f + ((float)row + 0.5f) * 0.5f * bin_h;
        const float xx = -rw * 0.5f + ((float)col + 0.5f) * 0.5f * bin_w;

        const float y = yy * cosv - xx * sinv + cy;
        const float x = yy * sinv + xx * cosv + cx;

        const bool inside = (y >= -1.0f) && (y <= (float)H_) &&
                            (x >= -1.0f) && (x <= (float)W_);

        const float yc = fmaxf(y, 0.0f);
        const float xc = fmaxf(x, 0.0f);
        const float fy = floorf(yc);
        const float fx = floorf(xc);
        int yl = min((int)fy, H_ - 1);
        int xl = min((int)fx, W_ - 1);
        const int yh = min(yl + 1, H_ - 1);
        const int xh = min(xl + 1, W_ - 1);
        const float ly = (fy >= (float)(H_ - 1)) ? 0.0f : (yc - fy);
        const float lx = (fx >= (float)(W_ - 1)) ? 0.0f : (xc - fx);
        const float hy = 1.0f - ly;
        const float hx = 1.0f - lx;

        const float m = inside ? 0.25f : 0.0f;   // fold inside-mask + 2x2 mean
        s_w[0][t] = hy * hx * m;
        s_w[1][t] = hy * lx * m;
        s_w[2][t] = ly * hx * m;
        s_w[3][t] = ly * lx * m;
        const int bb = fold_batch ? b : 0;
        s_idx[0][t] = ((bb * H_ + yl) * W_ + xl) * pix_stride;
        s_idx[1][t] = ((bb * H_ + yl) * W_ + xh) * pix_stride;
        s_idx[2][t] = ((bb * H_ + yh) * W_ + xl) * pix_stride;
        s_idx[3][t] = ((bb * H_ + yh) * W_ + xh) * pix_stride;
    }
}

// ---------- main kernel: whole ROI per block, high-MLP paired gathers -------
__global__ __launch_bounds__(256) void roi_main_nhwc_h(
    const __half* __restrict__ featT,
    const float* __restrict__ rois,
    float* __restrict__ out)
{
    __shared__ float  s_w[4][NSAMP];        // 3136 B
    __shared__ int    s_idx[4][NSAMP];      // 3136 B
    __shared__ __half s_out[49][258];       // 25284 B; total ~31.6 KB

    const int n = blockIdx.x;
    const int t = threadIdx.x;
    build_table(rois, n, t, s_w, s_idx, C_, 1, nullptr);
    __syncthreads();

    const int lane   = t & 63;
    const int wave   = t >> 6;
    const int half32 = lane >> 5;          // 0: corners {0,2}; 1: corners {1,3}
    const int ln     = lane & 31;
    const int cb     = ln * 8;             // 8 channels per lane (half-wave = 256)

    for (int bl = wave; bl < OUTHW * OUTHW; bl += 4) {
        const int oy = bl / OUTHW;
        const int ox = bl - oy * OUTHW;

        // ---- phase 1: compute all 8 paired-gather addresses + weights ----
        const __half* ptr[8];
        float wv[8];
        #pragma unroll
        for (int j = 0; j < 2; ++j) {
            #pragma unroll
            for (int i = 0; i < 2; ++i) {
                const int s = (oy * 2 + j) * GRID_S + (ox * 2 + i);
                const int k = (j * 2 + i) * 2;
                // pair A: corners (0|1) -> row yl; pair B: corners (2|3) -> yh
                const int iA = half32 ? s_idx[1][s] : s_idx[0][s];
                const int iB = half32 ? s_idx[3][s] : s_idx[2][s];
                wv[k]     = half32 ? s_w[1][s] : s_w[0][s];
                wv[k + 1] = half32 ? s_w[3][s] : s_w[2][s];
                ptr[k]     = featT + iA + cb;
                ptr[k + 1] = featT + iB + cb;
            }
        }

        // ---- phase 2: issue all 8 x 1KB gathers (8KB in flight) ----
        uint4 rv[8];
        #pragma unroll
        for (int k = 0; k < 8; ++k)
            rv[k] = *reinterpret_cast<const uint4*>(ptr[k]);

        // ---- phase 3: convert + weighted accumulate (8 ch per lane) ----
        float a[8] = {0.f, 0.f, 0.f, 0.f, 0.f, 0.f, 0.f, 0.f};
        #pragma unroll
        for (int k = 0; k < 8; ++k) {
            const __half2* h2 = reinterpret_cast<const __half2*>(&rv[k]);
            const float w = wv[k];
            #pragma unroll
            for (int m = 0; m < 4; ++m) {
                const float2 f = __half22float2(h2[m]);
                a[2 * m]     += w * f.x;
                a[2 * m + 1] += w * f.y;
            }
        }

        // ---- phase 4: combine half-wave partials, stage to LDS ----
        #pragma unroll
        for (int m = 0; m < 8; ++m)
            a[m] += __shfl_xor(a[m], 32, 64);
        if (half32 == 0) {
            // channel c = ln*8 + m stored at col m*32 + ln: 32 lanes hit 16
            // dword-banks x 2 = free
            #pragma unroll
            for (int m = 0; m < 8; ++m)
                s_out[bl][m * 32 + ln] = __float2half(a[m]);
        }
    }
    __syncthreads();

    // coalesced final stores: 1KB per wave-instruction, nontemporal stream
    float* __restrict__ ob = out + (size_t)n * ELEMS;
    for (int k = 0; k < 49; ++k) {
        const int e   = t + k * 256;
        const int c   = e / 49;
        const int bin = e - c * 49;
        // col for channel c: (c&7)*32 + (c>>3); lanes walk bins at ~fixed c
        // -> LDS row stride 129 dwords: conflict-free
        __builtin_nontemporal_store(
            __half2float(s_out[bin][(c & 7) * 32 + (c >> 3)]), &ob[e]);
    }
}

// ---------- fallback (known-correct NCHW path, no workspace) ----------
__global__ __launch_bounds__(256) void roi_main_nchw(
    const float* __restrict__ feat,
    const float* __restrict__ rois,
    float* __restrict__ out)
{
    const int n = blockIdx.x;
    const int t = threadIdx.x;
    __shared__ float s_w[4][NSAMP];
    __shared__ int   s_idx[4][NSAMP];
    __shared__ int   s_b;

    build_table(rois, n, t, s_w, s_idx, 1, 0, &s_b);
    __syncthreads();

    const float* __restrict__ fb = feat + (size_t)s_b * (size_t)(C_ * H_ * W_);
    float* __restrict__ ob = out + (size_t)n * (size_t)ELEMS;

    for (int e = t; e < ELEMS; e += 256) {
        const int c   = e / 49;
        const int bin = e - c * 49;
        const int oy  = bin / 7;
        const int ox  = bin - oy * 7;
        const float* __restrict__ fc = fb + c * (H_ * W_);
        float acc = 0.0f;
        #pragma unroll
        for (int j = 0; j < 2; ++j) {
            #pragma unroll
            for (int i = 0; i < 2; ++i) {
                const int s = (oy * 2 + j) * GRID_S + (ox * 2 + i);
                acc += s_w[0][s] * fc[s_idx[0][s]];
                acc += s_w[1][s] * fc[s_idx[1][s]];
                acc += s_w[2][s] * fc[s_idx[2][s]];
                acc += s_w[3][s] * fc[s_idx[3][s]];
            }
        }
        ob[e] = acc;
    }
}

extern "C" void kernel_launch(void* const* d_in, const int* in_sizes, int n_in,
                              void* d_out, int out_size, void* d_ws, size_t ws_size,
                              hipStream_t stream) {
    const float* feat = (const float*)d_in[0];
    const float* rois = (const float*)d_in[1];
    float* out = (float*)d_out;
    const int N = in_sizes[1] / 6;  // 1000

    const size_t need = (size_t)B_ * H_ * W_ * C_ * sizeof(__half); // 41 MB
    if (ws_size >= need) {
        __half* featT = (__half*)d_ws;
        dim3 tg((W_ + 63) / 64, C_ / 64, H_ * B_);
        transpose_h_kernel<<<tg, 256, 0, stream>>>(feat, featT);
        roi_main_nhwc_h<<<N, 256, 0, stream>>>(featT, rois, out);
    } else {
        roi_main_nchw<<<N, 256, 0, stream>>>(feat, rois, out);
    }
}

// Round 4
// 183.775 us; speedup vs baseline: 1.0536x; 1.0080x over previous
//
#include <hip/hip_runtime.h>
#include <hip/hip_fp16.h>

// RoIAlignRotated on MI355X — R6.
// R5 post-mortem: compiler refused to batch gathers (VGPR stayed 44 ->
// ~1 outstanding load/wave -> 1 load per ~40cy/CU, latency-serialized).
// R6: per-bin, issue ALL 16 uint2 gathers into named regs, then
// __builtin_amdgcn_sched_barrier(0) — an impenetrable scheduling fence —
// then consume in issue order (progressive vmcnt). Forces ~16 loads in
// flight per wave. Whole-ROI blocks (R3 shape): coalesced writes, one
// table build, L1 locality.

#define B_ 2
#define C_ 256
#define H_ 200
#define W_ 200
#define OUTHW 7
#define GRID_S 14          // OUTHW * sampling_ratio(2)
#define NSAMP 196          // 14*14
#define ELEMS (C_ * OUTHW * OUTHW)  // 12544

// ---------- NCHW f32 -> NHWC fp16, LDS-tiled ----------
__global__ __launch_bounds__(256) void transpose_h_kernel(
    const float* __restrict__ feat, __half* __restrict__ featT)
{
    __shared__ float tile[64][65];   // [c_local][x_local], stride 65
    const int x0   = blockIdx.x * 64;
    const int c0   = blockIdx.y * 64;
    const int yb   = blockIdx.z;     // b*H_ + y
    const int y    = yb % H_;
    const int b    = yb / H_;
    const int t    = threadIdx.x;
    const int lane = t & 63;
    const int grp  = t >> 6;         // 0..3
    const int nx   = min(64, W_ - x0);

    // read: lanes along x -> 256B coalesced per instruction
    if (lane < nx) {
        #pragma unroll
        for (int i = 0; i < 16; ++i) {
            const int cl = grp * 16 + i;
            tile[cl][lane] =
                feat[((size_t)(b * C_ + c0 + cl) * H_ + y) * W_ + x0 + lane];
        }
    }
    __syncthreads();

    // write: each lane packs 8 contiguous channels of one pixel -> 16B store.
    // Wave covers 8 pixels x 64 channels: 8 x 128B full-cache-line segments.
    const int c = (t & 7) * 8;
    #pragma unroll
    for (int pass = 0; pass < 2; ++pass) {
        const int p = pass * 32 + (t >> 3);
        if (p < nx) {
            union { __half h[8]; uint4 u; } pk;
            #pragma unroll
            for (int k = 0; k < 8; ++k)
                pk.h[k] = __float2half(tile[c + k][p]);
            *reinterpret_cast<uint4*>(
                &featT[((size_t)(b * H_ + y) * W_ + x0 + p) * C_ + c0 + c]) = pk.u;
        }
    }
}

// ---------- per-roi sample table (channel-independent) ----------
__device__ __forceinline__ void build_table(
    const float* __restrict__ rois, int n, int t,
    float s_w[4][NSAMP], int s_idx[4][NSAMP], int pix_stride, int fold_batch,
    int* s_b)
{
    const float spatial_scale = 0.25f;
    if (t == 0 && s_b) *s_b = (int)rois[n * 6 + 0];
    if (t < NSAMP) {
        const int   b  = (int)rois[n * 6 + 0];
        const float cx = rois[n * 6 + 1] * spatial_scale;
        const float cy = rois[n * 6 + 2] * spatial_scale;
        const float rw = fmaxf(rois[n * 6 + 3] * spatial_scale, 1.0f);
        const float rh = fmaxf(rois[n * 6 + 4] * spatial_scale, 1.0f);
        const float th = rois[n * 6 + 5];
        const float cosv = cosf(th), sinv = sinf(th);

        const float bin_h = rh * (1.0f / OUTHW);
        const float bin_w = rw * (1.0f / OUTHW);
        const int row = t / GRID_S;
        const int col = t % GRID_S;

        const float yy = -rh * 0.5f + ((float)row + 0.5f) * 0.5f * bin_h;
        const float xx = -rw * 0.5f + ((float)col + 0.5f) * 0.5f * bin_w;

        const float y = yy * cosv - xx * sinv + cy;
        const float x = yy * sinv + xx * cosv + cx;

        const bool inside = (y >= -1.0f) && (y <= (float)H_) &&
                            (x >= -1.0f) && (x <= (float)W_);

        const float yc = fmaxf(y, 0.0f);
        const float xc = fmaxf(x, 0.0f);
        const float fy = floorf(yc);
        const float fx = floorf(xc);
        int yl = min((int)fy, H_ - 1);
        int xl = min((int)fx, W_ - 1);
        const int yh = min(yl + 1, H_ - 1);
        const int xh = min(xl + 1, W_ - 1);
        const float ly = (fy >= (float)(H_ - 1)) ? 0.0f : (yc - fy);
        const float lx = (fx >= (float)(W_ - 1)) ? 0.0f : (xc - fx);
        const float hy = 1.0f - ly;
        const float hx = 1.0f - lx;

        const float m = inside ? 0.25f : 0.0f;   // fold inside-mask + 2x2 mean
        s_w[0][t] = hy * hx * m;
        s_w[1][t] = hy * lx * m;
        s_w[2][t] = ly * hx * m;
        s_w[3][t] = ly * lx * m;
        const int bb = fold_batch ? b : 0;
        s_idx[0][t] = ((bb * H_ + yl) * W_ + xl) * pix_stride;
        s_idx[1][t] = ((bb * H_ + yl) * W_ + xh) * pix_stride;
        s_idx[2][t] = ((bb * H_ + yh) * W_ + xl) * pix_stride;
        s_idx[3][t] = ((bb * H_ + yh) * W_ + xh) * pix_stride;
    }
}

// ---------- main kernel: whole ROI per block, forced 16-deep gather MLP ----
__global__ __launch_bounds__(256) void roi_main_nhwc_h(
    const __half* __restrict__ featT,
    const float* __restrict__ rois,
    float* __restrict__ out)
{
    __shared__ float  s_w[4][NSAMP];        // 3136 B
    __shared__ int    s_idx[4][NSAMP];      // 3136 B
    __shared__ __half s_out[49][258];       // 25284 B; total ~31.6 KB

    const int n = blockIdx.x;
    const int t = threadIdx.x;
    build_table(rois, n, t, s_w, s_idx, C_, 1, nullptr);
    __syncthreads();

    const int lane  = t & 63;
    const int wave  = t >> 6;
    const int cbase = lane * 4;        // 4 channels per lane

    for (int bl = wave; bl < OUTHW * OUTHW; bl += 4) {
        const int oy = bl / OUTHW;
        const int ox = bl - oy * OUTHW;

        // ---- phase 1: read all 16 (weight, offset) pairs from LDS ----
        int   off[16];
        float w[16];
        #pragma unroll
        for (int j = 0; j < 2; ++j) {
            #pragma unroll
            for (int i = 0; i < 2; ++i) {
                const int s = (oy * 2 + j) * GRID_S + (ox * 2 + i);
                #pragma unroll
                for (int q = 0; q < 4; ++q) {
                    const int k = (j * 2 + i) * 4 + q;
                    w[k]   = s_w[q][s];
                    off[k] = s_idx[q][s] + cbase;
                }
            }
        }

        // ---- phase 2: issue ALL 16 x 8B gathers (16 in flight) ----
        uint2 r[16];
        #pragma unroll
        for (int k = 0; k < 16; ++k)
            r[k] = *reinterpret_cast<const uint2*>(featT + off[k]);

        // impenetrable fence: loads may not sink, consumers may not hoist
        __builtin_amdgcn_sched_barrier(0);

        // ---- phase 3: consume in issue order (progressive vmcnt) ----
        float a0 = 0.f, a1 = 0.f, a2 = 0.f, a3 = 0.f;
        #pragma unroll
        for (int k = 0; k < 16; ++k) {
            const __half2* h2 = reinterpret_cast<const __half2*>(&r[k]);
            const float2 f0 = __half22float2(h2[0]);
            const float2 f1 = __half22float2(h2[1]);
            a0 += w[k] * f0.x; a1 += w[k] * f0.y;
            a2 += w[k] * f1.x; a3 += w[k] * f1.y;
        }

        // channel c=cbase+k at col k*64+lane: contiguous fp16 across lanes,
        // 2 lanes/dword-bank = free
        s_out[bl][0 * 64 + lane] = __float2half(a0);
        s_out[bl][1 * 64 + lane] = __float2half(a1);
        s_out[bl][2 * 64 + lane] = __float2half(a2);
        s_out[bl][3 * 64 + lane] = __float2half(a3);
    }
    __syncthreads();

    // coalesced final stores: 1KB per wave-instruction, nontemporal stream
    float* __restrict__ ob = out + (size_t)n * ELEMS;
    for (int k = 0; k < 49; ++k) {
        const int e   = t + k * 256;
        const int c   = e / 49;
        const int bin = e - c * 49;
        // lanes walk bins at ~fixed c -> LDS row stride 129 dwords: conflict-free
        __builtin_nontemporal_store(
            __half2float(s_out[bin][(c & 3) * 64 + (c >> 2)]), &ob[e]);
    }
}

// ---------- fallback (known-correct NCHW path, no workspace) ----------
__global__ __launch_bounds__(256) void roi_main_nchw(
    const float* __restrict__ feat,
    const float* __restrict__ rois,
    float* __restrict__ out)
{
    const int n = blockIdx.x;
    const int t = threadIdx.x;
    __shared__ float s_w[4][NSAMP];
    __shared__ int   s_idx[4][NSAMP];
    __shared__ int   s_b;

    build_table(rois, n, t, s_w, s_idx, 1, 0, &s_b);
    __syncthreads();

    const float* __restrict__ fb = feat + (size_t)s_b * (size_t)(C_ * H_ * W_);
    float* __restrict__ ob = out + (size_t)n * (size_t)ELEMS;

    for (int e = t; e < ELEMS; e += 256) {
        const int c   = e / 49;
        const int bin = e - c * 49;
        const int oy  = bin / 7;
        const int ox  = bin - oy * 7;
        const float* __restrict__ fc = fb + c * (H_ * W_);
        float acc = 0.0f;
        #pragma unroll
        for (int j = 0; j < 2; ++j) {
            #pragma unroll
            for (int i = 0; i < 2; ++i) {
                const int s = (oy * 2 + j) * GRID_S + (ox * 2 + i);
                acc += s_w[0][s] * fc[s_idx[0][s]];
                acc += s_w[1][s] * fc[s_idx[1][s]];
                acc += s_w[2][s] * fc[s_idx[2][s]];
                acc += s_w[3][s] * fc[s_idx[3][s]];
            }
        }
        ob[e] = acc;
    }
}

extern "C" void kernel_launch(void* const* d_in, const int* in_sizes, int n_in,
                              void* d_out, int out_size, void* d_ws, size_t ws_size,
                              hipStream_t stream) {
    const float* feat = (const float*)d_in[0];
    const float* rois = (const float*)d_in[1];
    float* out = (float*)d_out;
    const int N = in_sizes[1] / 6;  // 1000

    const size_t need = (size_t)B_ * H_ * W_ * C_ * sizeof(__half); // 41 MB
    if (ws_size >= need) {
        __half* featT = (__half*)d_ws;
        dim3 tg((W_ + 63) / 64, C_ / 64, H_ * B_);
        transpose_h_kernel<<<tg, 256, 0, stream>>>(feat, featT);
        roi_main_nhwc_h<<<N, 256, 0, stream>>>(featT, rois, out);
    } else {
        roi_main_nchw<<<N, 256, 0, stream>>>(feat, rois, out);
    }
}